// Round 4
// baseline (307.423 us; speedup 1.0000x reference)
//
#include <hip/hip_runtime.h>
#include <cstdint>

typedef _Float16 f16;
typedef _Float16 f16x8 __attribute__((ext_vector_type(8)));
typedef _Float16 f16x4 __attribute__((ext_vector_type(4)));
typedef float    f32x4 __attribute__((ext_vector_type(4)));

#define NB   8
#define SEQL 1024
#define EMB  1024
#define NH   16
#define HD   64
#define MR   (NB*SEQL)                        /* 8192 rows */
#define BHND ((size_t)NB*NH*SEQL*HD)          /* 8388608 elems per q/k/v buf */

// ---------------- async global->LDS (16B), CK-style addrspace cast ----------
static __device__ __forceinline__ void gload16(const void* g, void* l) {
  __builtin_amdgcn_global_load_lds(
      (const __attribute__((address_space(1))) char*)(uintptr_t)g,
      (__attribute__((address_space(3))) char*)(uintptr_t)l,
      16, 0, 0);
}

// ---------------- fp32 -> fp16 convert -------------------------------------
__global__ __launch_bounds__(256) void cvt_f32_f16(const float* __restrict__ src,
                                                   f16* __restrict__ dst, int n4) {
  int i = blockIdx.x * 256 + threadIdx.x;
  if (i >= n4) return;
  float4 v = ((const float4*)src)[i];
  f16x4 h;
  h[0] = (f16)v.x; h[1] = (f16)v.y; h[2] = (f16)v.z; h[3] = (f16)v.w;
  *(f16x4*)(dst + (size_t)i * 4) = h;
}

// ---------------- GEMM C = A[M,1024] * Bt[NTOT,1024]^T + bias ---------------
// MODE 0: scatter into q/k/v [b][h][n][d] fp16 buffers (outp = qkv base)
// MODE 1: C fp32 to outp ([row*NTOT + col])
template<int NTOT, int MODE>
__global__ __launch_bounds__(256, 2) void gemm_bt(const f16* __restrict__ A,
                                                  const f16* __restrict__ Bt,
                                                  const float* __restrict__ bias,
                                                  void* __restrict__ outp) {
  __shared__ char smem[32768];                 // A tile 16KB @0, B tile 16KB @16384
  const int t = threadIdx.x;
  const int w = t >> 6, lane = t & 63;
  const int lg = lane >> 4, lc = lane & 15;
  const int m0 = blockIdx.x * 128;
  const int n0 = blockIdx.y * 128;
  const int wr = w >> 1, wc = w & 1;

  f32x4 acc[4][4];
#pragma unroll
  for (int i = 0; i < 4; ++i)
#pragma unroll
    for (int j = 0; j < 4; ++j) acc[i][j] = (f32x4){0.f, 0.f, 0.f, 0.f};

  const char* Ab = (const char*)A + (size_t)m0 * 2048;   // 2048 B per row (1024 f16)
  const char* Bb = (const char*)Bt + (size_t)n0 * 2048;

  for (int k0 = 0; k0 < 1024; k0 += 64) {
    // stage 128x64 tiles of A and Bt; LDS linear dest, inverse-swizzled source
#pragma unroll
    for (int f = 0; f < 4; ++f) {
      const int ci = f * 4 + w;                 // wave-uniform chunk (1KB each)
      const int x = ci * 1024 + lane * 16;      // linear byte in tile
      const int row = x >> 7;                   // 128B per tile-row
      const int col = (x & 127) ^ ((row & 7) << 4);
      gload16(Ab + (size_t)row * 2048 + k0 * 2 + col, smem + ci * 1024);
      gload16(Bb + (size_t)row * 2048 + k0 * 2 + col, smem + 16384 + ci * 1024);
    }
    __syncthreads();

#pragma unroll
    for (int kk = 0; kk < 2; ++kk) {
      f16x8 af[4], bf[4];
#pragma unroll
      for (int i = 0; i < 4; ++i) {
        const int ra = wr * 64 + i * 16 + lc;
        int ba = ra * 128 + kk * 64 + lg * 16;
        ba ^= (ra & 7) << 4;                    // swizzled read
        af[i] = *(const f16x8*)(smem + ba);
        const int rb = wc * 64 + i * 16 + lc;
        int bb = rb * 128 + kk * 64 + lg * 16;
        bb ^= (rb & 7) << 4;
        bf[i] = *(const f16x8*)(smem + 16384 + bb);
      }
#pragma unroll
      for (int i = 0; i < 4; ++i)
#pragma unroll
        for (int j = 0; j < 4; ++j)
          acc[i][j] = __builtin_amdgcn_mfma_f32_16x16x32_f16(af[i], bf[j], acc[i][j], 0, 0, 0);
    }
    __syncthreads();
  }

  float biasv[4];
#pragma unroll
  for (int j = 0; j < 4; ++j) biasv[j] = bias[n0 + wc * 64 + j * 16 + lc];

  if (MODE == 1) {
    float* Out = (float*)outp;
#pragma unroll
    for (int i = 0; i < 4; ++i)
#pragma unroll
      for (int j = 0; j < 4; ++j) {
        const int colL = n0 + wc * 64 + j * 16 + lc;
#pragma unroll
        for (int r = 0; r < 4; ++r) {
          const int row = m0 + wr * 64 + i * 16 + lg * 4 + r;
          Out[(size_t)row * NTOT + colL] = acc[i][j][r] + biasv[j];
        }
      }
  } else {
    f16* qkv = (f16*)outp;
#pragma unroll
    for (int i = 0; i < 4; ++i) {
      const int rbase = m0 + wr * 64 + i * 16 + lg * 4;
#pragma unroll
      for (int j = 0; j < 4; ++j) {
        const int colL = n0 + wc * 64 + j * 16 + lc;
        const int which = colL >> 10;
        const int e = colL & 1023;
        const int h = e >> 6, d = e & 63;
#pragma unroll
        for (int r = 0; r < 4; ++r) {
          const int rr = rbase + r;
          const int b = rr >> 10, n = rr & 1023;
          qkv[(size_t)which * BHND + ((size_t)(b * NH + h) * SEQL + n) * HD + d] =
              (f16)(acc[i][j][r] + biasv[j]);
        }
      }
    }
  }
}

// ---------------- V [b][h][n][d] -> Vt [b][h][d][n] -------------------------
__global__ __launch_bounds__(256) void transpose_v(const f16* __restrict__ V,
                                                   f16* __restrict__ Vt) {
  __shared__ f16 tile[64 * 72];
  const int bid = blockIdx.x;
  const int bh = bid >> 4, nt = bid & 15;
  const int t = threadIdx.x;
  const int r = t >> 2, c0 = (t & 3) * 16;
  const f16* src = V + ((size_t)bh * SEQL + nt * 64 + r) * HD + c0;
  f16x8 a0 = *(const f16x8*)src;
  f16x8 a1 = *(const f16x8*)(src + 8);
#pragma unroll
  for (int e = 0; e < 8; ++e) {
    tile[(c0 + e) * 72 + r] = a0[e];
    tile[(c0 + 8 + e) * 72 + r] = a1[e];
  }
  __syncthreads();
  f16* dst = Vt + ((size_t)bh * HD + r) * SEQL + nt * 64 + c0;
  *(f16x8*)dst = *(const f16x8*)&tile[r * 72 + c0];
  *(f16x8*)(dst + 8) = *(const f16x8*)&tile[r * 72 + c0 + 8];
}

// ---------------- flash attention ------------------------------------------
// grid: (b*h)*16 + qtile ; 4 waves/block, 16 q-rows/wave, KV tiles of 64
__global__ __launch_bounds__(256, 2) void attn_fwd(const f16* __restrict__ Q,
                                                   const f16* __restrict__ Kh,
                                                   const f16* __restrict__ Vt,
                                                   f16* __restrict__ Oh) {
  __shared__ f16 Klds[64 * 72];
  __shared__ f16 Vlds[64 * 72];
  __shared__ float Plds[4][16 * 68];

  const int bid = blockIdx.x;
  const int bh = bid >> 4;       // b*NH + h
  const int qt = bid & 15;
  const int t = threadIdx.x;
  const int w = t >> 6, lane = t & 63;
  const int lg = lane >> 4, lc = lane & 15;

  // Q fragments: A-frag row = lc, k = kk*32 + lg*8 + j (contiguous)
  const f16* qrow = Q + ((size_t)bh * SEQL + qt * 64 + w * 16 + lc) * HD;
  const f16x8 qf0 = *(const f16x8*)(qrow + lg * 8);
  const f16x8 qf1 = *(const f16x8*)(qrow + 32 + lg * 8);

  f32x4 acc[4];
#pragma unroll
  for (int i = 0; i < 4; ++i) acc[i] = (f32x4){0.f, 0.f, 0.f, 0.f};
  float mrow[4], lrow[4];
#pragma unroll
  for (int r = 0; r < 4; ++r) { mrow[r] = -1e30f; lrow[r] = 0.f; }

  const int sr = t >> 2;                 // staging row 0..63
  const int sc = (t & 3) * 16;           // 0,16,32,48
  const f16* kbase = Kh + (size_t)bh * SEQL * HD;
  const f16* vbase = Vt + (size_t)bh * HD * SEQL;
  float* pw = &Plds[w][0];

  for (int kt = 0; kt < 16; ++kt) {
    {   // stage K [n][d] and Vt [d][n], padded rows (72 f16 = 144B -> 2-way)
      const f16* ks = kbase + (size_t)(kt * 64 + sr) * HD + sc;
      const f16* vs = vbase + (size_t)sr * SEQL + kt * 64 + sc;
      f16x8 k0 = *(const f16x8*)ks;
      f16x8 k1 = *(const f16x8*)(ks + 8);
      f16x8 v0 = *(const f16x8*)vs;
      f16x8 v1 = *(const f16x8*)(vs + 8);
      *(f16x8*)&Klds[sr * 72 + sc] = k0;
      *(f16x8*)&Klds[sr * 72 + sc + 8] = k1;
      *(f16x8*)&Vlds[sr * 72 + sc] = v0;
      *(f16x8*)&Vlds[sr * 72 + sc + 8] = v1;
    }
    __syncthreads();

    // S = Q K^T  (C-layout: S[q=lg*4+r][n = nt*16+lc])
    f32x4 s[4];
#pragma unroll
    for (int nt = 0; nt < 4; ++nt) s[nt] = (f32x4){0.f, 0.f, 0.f, 0.f};
#pragma unroll
    for (int nt = 0; nt < 4; ++nt) {
      f16x8 kf0 = *(const f16x8*)&Klds[(nt * 16 + lc) * 72 + lg * 8];
      f16x8 kf1 = *(const f16x8*)&Klds[(nt * 16 + lc) * 72 + 32 + lg * 8];
      s[nt] = __builtin_amdgcn_mfma_f32_16x16x32_f16(qf0, kf0, s[nt], 0, 0, 0);
      s[nt] = __builtin_amdgcn_mfma_f32_16x16x32_f16(qf1, kf1, s[nt], 0, 0, 0);
    }
#pragma unroll
    for (int nt = 0; nt < 4; ++nt) s[nt] = s[nt] * 0.125f;   // HEAD_DIM^-0.5

    // online softmax (rows lg*4+r live in this lane's 16-lane group)
#pragma unroll
    for (int r = 0; r < 4; ++r) {
      float mx = fmaxf(fmaxf(s[0][r], s[1][r]), fmaxf(s[2][r], s[3][r]));
#pragma unroll
      for (int off = 8; off >= 1; off >>= 1) mx = fmaxf(mx, __shfl_xor(mx, off, 64));
      const float nm = fmaxf(mrow[r], mx);
      const float al = __expf(mrow[r] - nm);
      mrow[r] = nm;
      float rs = 0.f;
#pragma unroll
      for (int nt = 0; nt < 4; ++nt) {
        const float p = __expf(s[nt][r] - nm);
        s[nt][r] = p;
        rs += p;
      }
#pragma unroll
      for (int off = 8; off >= 1; off >>= 1) rs += __shfl_xor(rs, off, 64);
      lrow[r] = lrow[r] * al + rs;
#pragma unroll
      for (int dt = 0; dt < 4; ++dt) acc[dt][r] *= al;
    }

    // P (C-layout) -> per-wave LDS [16][68]
#pragma unroll
    for (int r = 0; r < 4; ++r)
#pragma unroll
      for (int nt = 0; nt < 4; ++nt)
        pw[(lg * 4 + r) * 68 + nt * 16 + lc] = s[nt][r];
    asm volatile("s_waitcnt lgkmcnt(0)" ::: "memory");

    // O += P V   (A-frag: P[lc][kk*32+lg*8+j]; B-frag: Vt[dt*16+lc][...])
#pragma unroll
    for (int kk = 0; kk < 2; ++kk) {
      f32x4 p0 = *(const f32x4*)&pw[lc * 68 + kk * 32 + lg * 8];
      f32x4 p1 = *(const f32x4*)&pw[lc * 68 + kk * 32 + lg * 8 + 4];
      f16x8 pa;
#pragma unroll
      for (int e = 0; e < 4; ++e) { pa[e] = (f16)p0[e]; pa[e + 4] = (f16)p1[e]; }
#pragma unroll
      for (int dt = 0; dt < 4; ++dt) {
        f16x8 vf = *(const f16x8*)&Vlds[(dt * 16 + lc) * 72 + kk * 32 + lg * 8];
        acc[dt] = __builtin_amdgcn_mfma_f32_16x16x32_f16(pa, vf, acc[dt], 0, 0, 0);
      }
    }
    __syncthreads();
  }

  // epilogue: Oh is [b][n][h*64+d] fp16 (= proj GEMM A operand)
  const int b = bh >> 4, h = bh & 15;
  f16* ob = Oh + ((size_t)(b * SEQL) + qt * 64 + w * 16 + lg * 4) * EMB + h * 64;
#pragma unroll
  for (int r = 0; r < 4; ++r) {
    const float inv = 1.f / lrow[r];
#pragma unroll
    for (int dt = 0; dt < 4; ++dt)
      ob[(size_t)r * EMB + dt * 16 + lc] = (f16)(acc[dt][r] * inv);
  }
}

// ---------------- launcher --------------------------------------------------
extern "C" void kernel_launch(void* const* d_in, const int* in_sizes, int n_in,
                              void* d_out, int out_size, void* d_ws, size_t ws_size,
                              hipStream_t stream) {
  (void)in_sizes; (void)n_in; (void)out_size; (void)ws_size;
  const float* x      = (const float*)d_in[0];
  const float* w_qkv  = (const float*)d_in[1];
  const float* b_qkv  = (const float*)d_in[2];
  const float* w_proj = (const float*)d_in[3];
  const float* b_proj = (const float*)d_in[4];
  char* ws = (char*)d_ws;

  // workspace layout (72 MB total, with aliasing)
  const size_t XH = 0;                  // x fp16            16 MB (dead after gemm1)
  const size_t WQ = 16777216;           // w_qkv fp16         6 MB
  const size_t WP = 23068672;           // w_proj fp16        2 MB
  const size_t QH = 25165824;           // q [b][h][n][d]    16 MB
  const size_t KH = 41943040;           // k [b][h][n][d]    16 MB
  const size_t VH = 58720256;           // v [b][h][n][d]    16 MB (dead after transpose)
  const size_t VT = 0;                  // v^T [b][h][d][n]  16 MB (aliases XH)
  const size_t AH = VH;                 // attn out [b][n][e] (aliases VH)

  f16* xh  = (f16*)(ws + XH);
  f16* wqh = (f16*)(ws + WQ);
  f16* wph = (f16*)(ws + WP);

  cvt_f32_f16<<<(MR * EMB / 4 + 255) / 256, 256, 0, stream>>>(x, xh, MR * EMB / 4);
  cvt_f32_f16<<<(3 * EMB * EMB / 4 + 255) / 256, 256, 0, stream>>>(w_qkv, wqh, 3 * EMB * EMB / 4);
  cvt_f32_f16<<<(EMB * EMB / 4 + 255) / 256, 256, 0, stream>>>(w_proj, wph, EMB * EMB / 4);

  gemm_bt<3072, 0><<<dim3(64, 24), 256, 0, stream>>>(xh, wqh, b_qkv, (void*)(ws + QH));

  transpose_v<<<NB * NH * (SEQL / 64), 256, 0, stream>>>((const f16*)(ws + VH), (f16*)(ws + VT));

  attn_fwd<<<NB * NH * (SEQL / 64), 256, 0, stream>>>((const f16*)(ws + QH),
                                                      (const f16*)(ws + KH),
                                                      (const f16*)(ws + VT),
                                                      (f16*)(ws + AH));

  gemm_bt<1024, 1><<<dim3(64, 8), 256, 0, stream>>>((const f16*)(ws + AH), wph, b_proj, d_out);
}

// Round 6
// 248.220 us; speedup vs baseline: 1.2385x; 1.2385x over previous
//
#include <hip/hip_runtime.h>
#include <cstdint>

typedef _Float16 f16;
typedef _Float16 f16x8 __attribute__((ext_vector_type(8)));
typedef _Float16 f16x4 __attribute__((ext_vector_type(4)));
typedef _Float16 f16x2 __attribute__((ext_vector_type(2)));
typedef float    f32x4 __attribute__((ext_vector_type(4)));
typedef float    f32x16 __attribute__((ext_vector_type(16)));
typedef unsigned int uint;

#define NB   8
#define SEQL 1024
#define EMB  1024
#define NH   16
#define HD   64
#define MR   (NB*SEQL)                        /* 8192 rows */
#define BHND ((size_t)NB*NH*SEQL*HD)          /* 8388608 elems per q/k/v buf */

// ---------------- async global->LDS (16B) ----------------------------------
static __device__ __forceinline__ void gload16(const void* g, void* l) {
  __builtin_amdgcn_global_load_lds(
      (const __attribute__((address_space(1))) char*)(uintptr_t)g,
      (__attribute__((address_space(3))) char*)(uintptr_t)l,
      16, 0, 0);
}

static __device__ __forceinline__ uint packf16(float a, float b) {
  f16x2 h; h[0] = (f16)a; h[1] = (f16)b;
  return __builtin_bit_cast(uint, h);
}

// ---------------- fp32 -> fp16 convert -------------------------------------
__global__ __launch_bounds__(256) void cvt_f32_f16(const float* __restrict__ src,
                                                   f16* __restrict__ dst, int n4) {
  int i = blockIdx.x * 256 + threadIdx.x;
  if (i >= n4) return;
  float4 v = ((const float4*)src)[i];
  f16x4 h;
  h[0] = (f16)v.x; h[1] = (f16)v.y; h[2] = (f16)v.z; h[3] = (f16)v.w;
  *(f16x4*)(dst + (size_t)i * 4) = h;
}

// ---------------- GEMM C = A[M,1024] * Bt[NTOT,1024]^T + bias ---------------
template<int NTOT, int MODE>
__global__ __launch_bounds__(256, 2) void gemm_bt(const f16* __restrict__ A,
                                                  const f16* __restrict__ Bt,
                                                  const float* __restrict__ bias,
                                                  void* __restrict__ outp) {
  __shared__ char smem[32768];
  const int t = threadIdx.x;
  const int w = t >> 6, lane = t & 63;
  const int lg = lane >> 4, lc = lane & 15;
  const int m0 = blockIdx.x * 128;
  const int n0 = blockIdx.y * 128;
  const int wr = w >> 1, wc = w & 1;

  f32x4 acc[4][4];
#pragma unroll
  for (int i = 0; i < 4; ++i)
#pragma unroll
    for (int j = 0; j < 4; ++j) acc[i][j] = (f32x4){0.f, 0.f, 0.f, 0.f};

  const char* Ab = (const char*)A + (size_t)m0 * 2048;
  const char* Bb = (const char*)Bt + (size_t)n0 * 2048;

  for (int k0 = 0; k0 < 1024; k0 += 64) {
#pragma unroll
    for (int f = 0; f < 4; ++f) {
      const int ci = f * 4 + w;
      const int x = ci * 1024 + lane * 16;
      const int row = x >> 7;
      const int col = (x & 127) ^ ((row & 7) << 4);
      gload16(Ab + (size_t)row * 2048 + k0 * 2 + col, smem + ci * 1024);
      gload16(Bb + (size_t)row * 2048 + k0 * 2 + col, smem + 16384 + ci * 1024);
    }
    __syncthreads();

#pragma unroll
    for (int kk = 0; kk < 2; ++kk) {
      f16x8 af[4], bf[4];
#pragma unroll
      for (int i = 0; i < 4; ++i) {
        const int ra = wr * 64 + i * 16 + lc;
        int ba = ra * 128 + kk * 64 + lg * 16;
        ba ^= (ra & 7) << 4;
        af[i] = *(const f16x8*)(smem + ba);
        const int rb = wc * 64 + i * 16 + lc;
        int bb = rb * 128 + kk * 64 + lg * 16;
        bb ^= (rb & 7) << 4;
        bf[i] = *(const f16x8*)(smem + 16384 + bb);
      }
#pragma unroll
      for (int i = 0; i < 4; ++i)
#pragma unroll
        for (int j = 0; j < 4; ++j)
          acc[i][j] = __builtin_amdgcn_mfma_f32_16x16x32_f16(af[i], bf[j], acc[i][j], 0, 0, 0);
    }
    __syncthreads();
  }

  float biasv[4];
#pragma unroll
  for (int j = 0; j < 4; ++j) biasv[j] = bias[n0 + wc * 64 + j * 16 + lc];

  if (MODE == 1) {
    float* Out = (float*)outp;
#pragma unroll
    for (int i = 0; i < 4; ++i)
#pragma unroll
      for (int j = 0; j < 4; ++j) {
        const int colL = n0 + wc * 64 + j * 16 + lc;
#pragma unroll
        for (int r = 0; r < 4; ++r) {
          const int row = m0 + wr * 64 + i * 16 + lg * 4 + r;
          Out[(size_t)row * NTOT + colL] = acc[i][j][r] + biasv[j];
        }
      }
  } else {
    f16* qkv = (f16*)outp;
#pragma unroll
    for (int i = 0; i < 4; ++i) {
      const int rbase = m0 + wr * 64 + i * 16 + lg * 4;
#pragma unroll
      for (int j = 0; j < 4; ++j) {
        const int colL = n0 + wc * 64 + j * 16 + lc;
        const int which = colL >> 10;
        const int e = colL & 1023;
        const int h = e >> 6, d = e & 63;
#pragma unroll
        for (int r = 0; r < 4; ++r) {
          const int rr = rbase + r;
          const int b = rr >> 10, n = rr & 1023;
          qkv[(size_t)which * BHND + ((size_t)(b * NH + h) * SEQL + n) * HD + d] =
              (f16)(acc[i][j][r] + biasv[j]);
        }
      }
    }
  }
}

// ---------------- V [b][h][n][d] -> Vt [b][h][d][n] -------------------------
__global__ __launch_bounds__(256) void transpose_v(const f16* __restrict__ V,
                                                   f16* __restrict__ Vt) {
  __shared__ f16 tile[64 * 72];
  const int bid = blockIdx.x;
  const int bh = bid >> 4, nt = bid & 15;
  const int t = threadIdx.x;
  const int r = t >> 2, c0 = (t & 3) * 16;
  const f16* src = V + ((size_t)bh * SEQL + nt * 64 + r) * HD + c0;
  f16x8 a0 = *(const f16x8*)src;
  f16x8 a1 = *(const f16x8*)(src + 8);
#pragma unroll
  for (int e = 0; e < 8; ++e) {
    tile[(c0 + e) * 72 + r] = a0[e];
    tile[(c0 + 8 + e) * 72 + r] = a1[e];
  }
  __syncthreads();
  f16* dst = Vt + ((size_t)bh * HD + r) * SEQL + nt * 64 + c0;
  *(f16x8*)dst = *(const f16x8*)&tile[r * 72 + c0];
  *(f16x8*)(dst + 8) = *(const f16x8*)&tile[r * 72 + c0 + 8];
}

// ---------------- flash attention, swapped 32x32x16 MFMA --------------------
// grid: (b*h)*8 + qblock ; 4 waves/block, 32 q-rows/wave (128/block), KV tiles 64
// S^T = mfma(K, Q): lane owns q = lane&31 (stats lane-local)
// O^T = mfma(Vt, P^T): acc col = q = lane&31 (rescale lane-local)
__global__ __launch_bounds__(256, 2) void attn_fwd(const f16* __restrict__ Q,
                                                   const f16* __restrict__ Kh,
                                                   const f16* __restrict__ Vt,
                                                   f16* __restrict__ Oh) {
  __shared__ uint4 Kl4[512];   // 8 KB: K tile [n=64][d=64] f16, XOR-swizzled
  __shared__ uint4 Vl4[512];   // 8 KB: Vt tile [d=64][n=64] f16, XOR-swizzled
  char* Kl = (char*)Kl4;
  char* Vl = (char*)Vl4;

  const int bid = blockIdx.x;
  const int bh = bid >> 3;           // b*NH + h
  const int qb = bid & 7;
  const int t = threadIdx.x;
  const int w = t >> 6, lane = t & 63;
  const int l31 = lane & 31, hi = lane >> 5;

  const char* kbp = (const char*)Kh + (size_t)bh * 131072;   // SEQL*HD*2 bytes
  const char* vbp = (const char*)Vt + (size_t)bh * 131072;

  // Q fragment (B-operand of S^T): B[d][q]: col=q=l31, k=d = dc*16 + hi*8 + j
  // scale 0.125 folded in (exact power of 2 in f16)
  const f16* qp = Q + ((size_t)bh * SEQL + qb * 128 + w * 32 + l31) * HD;
  f16x8 qf[4];
#pragma unroll
  for (int dc = 0; dc < 4; ++dc) {
    f16x8 v = *(const f16x8*)(qp + dc * 16 + hi * 8);
#pragma unroll
    for (int e = 0; e < 8; ++e) v[e] = v[e] * (f16)0.125f;
    qf[dc] = v;
  }

  f32x16 acc0, acc1;
#pragma unroll
  for (int i = 0; i < 16; ++i) { acc0[i] = 0.f; acc1[i] = 0.f; }
  float m = -1e30f, l = 0.f;

  for (int kt = 0; kt < 16; ++kt) {
    // ---- stage K and Vt tiles (16 KB total, 4 gload16 per wave) ----
#pragma unroll
    for (int f = 0; f < 2; ++f) {
      const int ci = w * 2 + f;                 // wave-uniform chunk (1 KB)
      const int x = ci * 1024 + lane * 16;      // linear byte in tile
      const int row = x >> 7;                   // 128 B per tile-row
      const int col = (x & 127) ^ ((row & 7) << 4);   // inverse-swizzled source
      gload16(kbp + (size_t)(kt * 64 + row) * 128 + col, Kl + ci * 1024);
      gload16(vbp + (size_t)row * 2048 + kt * 128 + col, Vl + ci * 1024);
    }
    __syncthreads();

    // ---- S^T = K · Q : C col = q = l31, row = k over regs ----
    f32x16 s0, s1;
#pragma unroll
    for (int i = 0; i < 16; ++i) { s0[i] = 0.f; s1[i] = 0.f; }
#pragma unroll
    for (int dc = 0; dc < 4; ++dc) {
      const int cb = dc * 32 + hi * 16;
      const int a0 = (l31 * 128 + cb) ^ ((l31 & 7) << 4);
      const int a1 = ((l31 + 32) * 128 + cb) ^ ((l31 & 7) << 4);
      f16x8 kf0 = *(const f16x8*)(Kl + a0);
      f16x8 kf1 = *(const f16x8*)(Kl + a1);
      s0 = __builtin_amdgcn_mfma_f32_32x32x16_f16(kf0, qf[dc], s0, 0, 0, 0);
      s1 = __builtin_amdgcn_mfma_f32_32x32x16_f16(kf1, qf[dc], s1, 0, 0, 0);
    }

    // ---- lane-local online softmax (k = (reg&3)+8*(reg>>2)+4*hi + 32*ksub) ----
    float v[32];
#pragma unroll
    for (int i = 0; i < 16; ++i) { v[i] = s0[i]; v[16 + i] = s1[i]; }
#pragma unroll
    for (int st = 16; st >= 1; st >>= 1)
#pragma unroll
      for (int i = 0; i < st; ++i) v[i] = fmaxf(v[i], v[i + st]);
    const float mx = fmaxf(v[0], __shfl_xor(v[0], 32));
    const float nm = fmaxf(m, mx);
    const float al = __expf(m - nm);
    m = nm;
    float p[32];
#pragma unroll
    for (int i = 0; i < 16; ++i) {
      p[i] = __expf(s0[i] - nm);
      p[16 + i] = __expf(s1[i] - nm);
    }
    float ts[32];
#pragma unroll
    for (int i = 0; i < 32; ++i) ts[i] = p[i];
#pragma unroll
    for (int st = 16; st >= 1; st >>= 1)
#pragma unroll
      for (int i = 0; i < st; ++i) ts[i] += ts[i + st];
    const float rs = ts[0] + __shfl_xor(ts[0], 32);
    l = l * al + rs;
    acc0 *= al;
    acc1 *= al;

    // ---- pack P to f16 pairs; exchange halves for B-fragment ----
    uint wk[16], xk[16];
#pragma unroll
    for (int i = 0; i < 16; ++i) wk[i] = packf16(p[2 * i], p[2 * i + 1]);
#pragma unroll
    for (int i = 0; i < 16; ++i) xk[i] = __shfl_xor(wk[i], 32);

    // ---- O^T += Vt · P^T ----
#pragma unroll
    for (int ksub = 0; ksub < 2; ++ksub)
#pragma unroll
      for (int kh = 0; kh < 2; ++kh) {
        const int b0 = ksub * 8 + kh * 4;
        union { uint u[4]; f16x8 v; } fb;
        fb.u[0] = hi ? xk[b0 + 2] : wk[b0 + 0];
        fb.u[1] = hi ? xk[b0 + 3] : wk[b0 + 1];
        fb.u[2] = hi ? wk[b0 + 2] : xk[b0 + 0];
        fb.u[3] = hi ? wk[b0 + 3] : xk[b0 + 1];
        const int cb = ksub * 64 + kh * 32 + hi * 16;
        const int av0 = (l31 * 128 + cb) ^ ((l31 & 7) << 4);
        const int av1 = ((l31 + 32) * 128 + cb) ^ ((l31 & 7) << 4);
        f16x8 vf0 = *(const f16x8*)(Vl + av0);
        f16x8 vf1 = *(const f16x8*)(Vl + av1);
        acc0 = __builtin_amdgcn_mfma_f32_32x32x16_f16(vf0, fb.v, acc0, 0, 0, 0);
        acc1 = __builtin_amdgcn_mfma_f32_32x32x16_f16(vf1, fb.v, acc1, 0, 0, 0);
      }
    __syncthreads();
  }

  // ---- epilogue: O row = q (lane-local l), d = (r&3)+8*(r>>2)+4*hi+32*dsub ----
  const int b = bh >> 4, h = bh & 15;
  const float inv = 1.f / l;
  f16* ob = Oh + ((size_t)(b * SEQL) + qb * 128 + w * 32 + l31) * EMB + h * 64;
#pragma unroll
  for (int g = 0; g < 4; ++g) {
    f16x4 o0, o1;
#pragma unroll
    for (int e = 0; e < 4; ++e) {
      o0[e] = (f16)(acc0[g * 4 + e] * inv);
      o1[e] = (f16)(acc1[g * 4 + e] * inv);
    }
    *(f16x4*)(ob + g * 8 + hi * 4) = o0;
    *(f16x4*)(ob + 32 + g * 8 + hi * 4) = o1;
  }
}

// ---------------- launcher --------------------------------------------------
extern "C" void kernel_launch(void* const* d_in, const int* in_sizes, int n_in,
                              void* d_out, int out_size, void* d_ws, size_t ws_size,
                              hipStream_t stream) {
  (void)in_sizes; (void)n_in; (void)out_size; (void)ws_size;
  const float* x      = (const float*)d_in[0];
  const float* w_qkv  = (const float*)d_in[1];
  const float* b_qkv  = (const float*)d_in[2];
  const float* w_proj = (const float*)d_in[3];
  const float* b_proj = (const float*)d_in[4];
  char* ws = (char*)d_ws;

  // workspace layout (72 MB total, with aliasing)
  const size_t XH = 0;                  // x fp16            16 MB (dead after gemm1)
  const size_t WQ = 16777216;           // w_qkv fp16         6 MB
  const size_t WP = 23068672;           // w_proj fp16        2 MB
  const size_t QH = 25165824;           // q [b][h][n][d]    16 MB
  const size_t KH = 41943040;           // k [b][h][n][d]    16 MB
  const size_t VH = 58720256;           // v [b][h][n][d]    16 MB (dead after transpose)
  const size_t VT = 0;                  // v^T [b][h][d][n]  16 MB (aliases XH)
  const size_t AH = VH;                 // attn out [b][n][e] (aliases VH)

  f16* xh  = (f16*)(ws + XH);
  f16* wqh = (f16*)(ws + WQ);
  f16* wph = (f16*)(ws + WP);

  cvt_f32_f16<<<(MR * EMB / 4 + 255) / 256, 256, 0, stream>>>(x, xh, MR * EMB / 4);
  cvt_f32_f16<<<(3 * EMB * EMB / 4 + 255) / 256, 256, 0, stream>>>(w_qkv, wqh, 3 * EMB * EMB / 4);
  cvt_f32_f16<<<(EMB * EMB / 4 + 255) / 256, 256, 0, stream>>>(w_proj, wph, EMB * EMB / 4);

  gemm_bt<3072, 0><<<dim3(64, 24), 256, 0, stream>>>(xh, wqh, b_qkv, (void*)(ws + QH));

  transpose_v<<<NB * NH * (SEQL / 64), 256, 0, stream>>>((const f16*)(ws + VH), (f16*)(ws + VT));

  attn_fwd<<<NB * NH * 8, 256, 0, stream>>>((const f16*)(ws + QH),
                                            (const f16*)(ws + KH),
                                            (const f16*)(ws + VT),
                                            (f16*)(ws + AH));

  gemm_bt<1024, 1><<<dim3(64, 8), 256, 0, stream>>>((const f16*)(ws + AH), wph, b_proj, d_out);
}